// Round 3
// baseline (232.757 us; speedup 1.0000x reference)
//
#include <hip/hip_runtime.h>
#include <hip/hip_bf16.h>

typedef __attribute__((ext_vector_type(8))) short short8v;
typedef __attribute__((ext_vector_type(4))) float f32x4;

#define N_EDGES 1000000
#define NROWS   (N_EDGES * 3)
#define NTILES  (NROWS / 16)   // 187500 exactly

__device__ __forceinline__ unsigned short f2bf(float f) {
    unsigned u = __builtin_bit_cast(unsigned, f);
    u += 0x7fffu + ((u >> 16) & 1u);           // round-to-nearest-even
    return (unsigned short)(u >> 16);
}

// Build combined 64x32 bf16 matrix Mc in workspace:
//   rows 0..31  : 0.5*M1 + 0.25*M2   (multiplies a = W .* x_src)
//   rows 32..63 : -0.5*M1 + 0.25*M2  (multiplies b = W .* x_dst)
__global__ void build_mc(const float* __restrict__ M1, const float* __restrict__ M2,
                         unsigned short* __restrict__ mc) {
    int i = blockIdx.x * blockDim.x + threadIdx.x;
    if (i >= 64 * 32) return;
    int k = i >> 5;
    int f = i & 31;
    float v;
    if (k < 32) v =  0.5f * M1[k * 32 + f]        + 0.25f * M2[k * 32 + f];
    else        v = -0.5f * M1[(k - 32) * 32 + f] + 0.25f * M2[(k - 32) * 32 + f];
    mc[i] = f2bf(v);
}

struct G6 { f32x4 w0, w1, s0, s1, t0, t1; };

__global__ __launch_bounds__(256) void n2e_main(
    const float* __restrict__ xn,
    const int*   __restrict__ src_idx,
    const int*   __restrict__ dst_idx,
    const float* __restrict__ W,
    const unsigned short* __restrict__ mc,
    float* __restrict__ out)
{
    const int lane = threadIdx.x & 63;
    const int wid  = threadIdx.x >> 6;
    const int col  = lane & 15;        // A row / D col / B col
    const int kg   = lane >> 4;        // 0..3
    const int kk   = kg << 3;          // k-offset of this lane's 8 elements

    // B fragments: lane holds B[k=(lane>>4)*8+i][col]
    short8v B00, B01, B10, B11;
    #pragma unroll
    for (int i = 0; i < 8; ++i) {
        int k0 = (kk + i) * 32;            // chunk 0 rows 0..31
        int k1 = (32 + kk + i) * 32;       // chunk 1 rows 32..63
        B00[i] = (short)mc[k0 + col];
        B01[i] = (short)mc[k0 + 16 + col];
        B10[i] = (short)mc[k1 + col];
        B11[i] = (short)mc[k1 + 16 + col];
    }

    // balanced contiguous chunk of tiles per wave
    const int NW = gridDim.x * 4;
    const int gw = blockIdx.x * 4 + wid;
    const int q  = NTILES / NW;
    const int rr = NTILES % NW;
    int t0, cnt;
    if (gw < rr) { cnt = q + 1; t0 = gw * cnt; }
    else         { cnt = q;     t0 = rr * (q + 1) + (gw - rr) * q; }
    if (cnt <= 0) return;
    const int tlast = t0 + cnt - 1;

    // ---- prologue: idx for t0 and t0+1, data for t0 ----
    int row0 = (t0 << 4) + col;
    int e0 = (int)((unsigned)row0 / 3u);
    int d0 = row0 - e0 * 3;
    int sA = __builtin_nontemporal_load(src_idx + e0);
    int tA = __builtin_nontemporal_load(dst_idx + e0);

    int tn1 = t0 + 1 <= tlast ? t0 + 1 : tlast;
    int row1 = (tn1 << 4) + col;
    int e1 = (int)((unsigned)row1 / 3u);
    int sB = __builtin_nontemporal_load(src_idx + e1);
    int tB = __builtin_nontemporal_load(dst_idx + e1);

    G6 gcur;
    {
        const float* wp = W  + (size_t)e0 * 32 + kk;
        const float* sp = xn + ((size_t)sA * 3 + d0) * 32 + kk;
        const float* tp = xn + ((size_t)tA * 3 + d0) * 32 + kk;
        gcur.w0 = __builtin_nontemporal_load((const f32x4*)wp);
        gcur.w1 = __builtin_nontemporal_load((const f32x4*)(wp + 4));
        gcur.s0 = *(const f32x4*)sp;
        gcur.s1 = *(const f32x4*)(sp + 4);
        gcur.t0 = *(const f32x4*)tp;
        gcur.t1 = *(const f32x4*)(tp + 4);
    }

    for (int j = 0; j < cnt; ++j) {
        const int tc = t0 + j;

        // ---- issue next tile's data loads (uses idx prefetched 2 iters ago) ----
        int tn = tc + 1 <= tlast ? tc + 1 : tlast;
        int rown = (tn << 4) + col;
        int en = (int)((unsigned)rown / 3u);
        int dn = rown - en * 3;
        G6 gnxt;
        {
            const float* wp = W  + (size_t)en * 32 + kk;
            const float* sp = xn + ((size_t)sB * 3 + dn) * 32 + kk;
            const float* tp = xn + ((size_t)tB * 3 + dn) * 32 + kk;
            gnxt.w0 = __builtin_nontemporal_load((const f32x4*)wp);
            gnxt.w1 = __builtin_nontemporal_load((const f32x4*)(wp + 4));
            gnxt.s0 = *(const f32x4*)sp;
            gnxt.s1 = *(const f32x4*)(sp + 4);
            gnxt.t0 = *(const f32x4*)tp;
            gnxt.t1 = *(const f32x4*)(tp + 4);
        }

        // ---- issue idx loads 2 tiles ahead ----
        int t2 = tc + 2 <= tlast ? tc + 2 : tlast;
        int row2 = (t2 << 4) + col;
        int e2 = (int)((unsigned)row2 / 3u);
        int sC = __builtin_nontemporal_load(src_idx + e2);
        int tC = __builtin_nontemporal_load(dst_idx + e2);

        // ---- compute current tile from gcur ----
        union { short8v v; __hip_bfloat162 h[4]; } ua, ub;
        ua.h[0] = __float22bfloat162_rn(make_float2(gcur.w0.x * gcur.s0.x, gcur.w0.y * gcur.s0.y));
        ua.h[1] = __float22bfloat162_rn(make_float2(gcur.w0.z * gcur.s0.z, gcur.w0.w * gcur.s0.w));
        ua.h[2] = __float22bfloat162_rn(make_float2(gcur.w1.x * gcur.s1.x, gcur.w1.y * gcur.s1.y));
        ua.h[3] = __float22bfloat162_rn(make_float2(gcur.w1.z * gcur.s1.z, gcur.w1.w * gcur.s1.w));
        ub.h[0] = __float22bfloat162_rn(make_float2(gcur.w0.x * gcur.t0.x, gcur.w0.y * gcur.t0.y));
        ub.h[1] = __float22bfloat162_rn(make_float2(gcur.w0.z * gcur.t0.z, gcur.w0.w * gcur.t0.w));
        ub.h[2] = __float22bfloat162_rn(make_float2(gcur.w1.x * gcur.t1.x, gcur.w1.y * gcur.t1.y));
        ub.h[3] = __float22bfloat162_rn(make_float2(gcur.w1.z * gcur.t1.z, gcur.w1.w * gcur.t1.w));

        f32x4 acc0 = {0.f, 0.f, 0.f, 0.f};
        f32x4 acc1 = {0.f, 0.f, 0.f, 0.f};
        acc0 = __builtin_amdgcn_mfma_f32_16x16x32_bf16(ua.v, B00, acc0, 0, 0, 0);
        acc0 = __builtin_amdgcn_mfma_f32_16x16x32_bf16(ub.v, B10, acc0, 0, 0, 0);
        acc1 = __builtin_amdgcn_mfma_f32_16x16x32_bf16(ua.v, B01, acc1, 0, 0, 0);
        acc1 = __builtin_amdgcn_mfma_f32_16x16x32_bf16(ub.v, B11, acc1, 0, 0, 0);

        // D: col = lane&15, row = tc*16 + kg*4 + i  — nontemporal stores
        float* op = out + (size_t)((tc << 4) + (kg << 2)) * 32 + col;
        #pragma unroll
        for (int i = 0; i < 4; ++i) {
            __builtin_nontemporal_store(acc0[i], op + (size_t)i * 32);
            __builtin_nontemporal_store(acc1[i], op + (size_t)i * 32 + 16);
        }

        // rotate pipeline registers
        gcur = gnxt;
        sB = sC; tB = tC;
    }
}

extern "C" void kernel_launch(void* const* d_in, const int* in_sizes, int n_in,
                              void* d_out, int out_size, void* d_ws, size_t ws_size,
                              hipStream_t stream) {
    const float* xn  = (const float*)d_in[0];
    const int*   xs  = (const int*)  d_in[1];
    const int*   xd  = (const int*)  d_in[2];
    const float* W   = (const float*)d_in[3];
    const float* M1  = (const float*)d_in[4];
    const float* M2  = (const float*)d_in[5];
    float* out = (float*)d_out;
    unsigned short* mc = (unsigned short*)d_ws;

    hipLaunchKernelGGL(build_mc, dim3(8), dim3(256), 0, stream, M1, M2, mc);
    hipLaunchKernelGGL(n2e_main, dim3(2048), dim3(256), 0, stream,
                       xn, xs, xd, W, mc, out);
}

// Round 4
// 214.217 us; speedup vs baseline: 1.0865x; 1.0865x over previous
//
#include <hip/hip_runtime.h>
#include <hip/hip_bf16.h>

typedef __attribute__((ext_vector_type(8))) short short8v;
typedef __attribute__((ext_vector_type(4))) float f32x4;

#define N_EDGES 1000000
#define NROWS   (N_EDGES * 3)
#define NTILES  (NROWS / 16)   // 187500 exactly
#define XN_ELEMS (50000 * 3 * 32)

__device__ __forceinline__ unsigned short f2bf(float f) {
    unsigned u = __builtin_bit_cast(unsigned, f);
    u += 0x7fffu + ((u >> 16) & 1u);           // round-to-nearest-even
    return (unsigned short)(u >> 16);
}

// Build combined 64x32 bf16 matrix Mc in workspace:
//   rows 0..31  : 0.5*M1 + 0.25*M2   (multiplies a = W .* x_src)
//   rows 32..63 : -0.5*M1 + 0.25*M2  (multiplies b = W .* x_dst)
__global__ void build_mc(const float* __restrict__ M1, const float* __restrict__ M2,
                         unsigned short* __restrict__ mc) {
    int i = blockIdx.x * blockDim.x + threadIdx.x;
    if (i >= 64 * 32) return;
    int k = i >> 5;
    int f = i & 31;
    float v;
    if (k < 32) v =  0.5f * M1[k * 32 + f]        + 0.25f * M2[k * 32 + f];
    else        v = -0.5f * M1[(k - 32) * 32 + f] + 0.25f * M2[(k - 32) * 32 + f];
    mc[i] = f2bf(v);
}

typedef __attribute__((ext_vector_type(4))) unsigned short u16x4;

// Convert xn (fp32) -> bf16 copy in workspace (halves gather bytes, 4x fewer
// gather transactions in the main kernel).
__global__ __launch_bounds__(256) void convert_xn(const float* __restrict__ xn,
                                                  unsigned short* __restrict__ xb) {
    const int n4 = XN_ELEMS / 4;
    int i = blockIdx.x * blockDim.x + threadIdx.x;
    const int stride = gridDim.x * blockDim.x;
    for (; i < n4; i += stride) {
        f32x4 v = __builtin_nontemporal_load((const f32x4*)xn + i);
        u16x4 o;
        o[0] = f2bf(v.x); o[1] = f2bf(v.y); o[2] = f2bf(v.z); o[3] = f2bf(v.w);
        *((u16x4*)xb + i) = o;
    }
}

struct G4 { f32x4 w0, w1; short8v xs, xt; };

__global__ __launch_bounds__(256) void n2e_main(
    const unsigned short* __restrict__ xb,   // bf16 xn copy (ws)
    const int*   __restrict__ src_idx,
    const int*   __restrict__ dst_idx,
    const float* __restrict__ W,
    const unsigned short* __restrict__ mc,
    float* __restrict__ out)
{
    const int lane = threadIdx.x & 63;
    const int wid  = threadIdx.x >> 6;
    const int col  = lane & 15;        // A row / D col / B col
    const int kg   = lane >> 4;        // 0..3
    const int kk   = kg << 3;          // k-offset of this lane's 8 elements

    // B fragments: lane holds B[k=(lane>>4)*8+i][col]
    short8v B00, B01, B10, B11;
    #pragma unroll
    for (int i = 0; i < 8; ++i) {
        int k0 = (kk + i) * 32;            // chunk 0 rows 0..31
        int k1 = (32 + kk + i) * 32;       // chunk 1 rows 32..63
        B00[i] = (short)mc[k0 + col];
        B01[i] = (short)mc[k0 + 16 + col];
        B10[i] = (short)mc[k1 + col];
        B11[i] = (short)mc[k1 + 16 + col];
    }

    // balanced contiguous chunk of tiles per wave
    const int NW = gridDim.x * 4;
    const int gw = blockIdx.x * 4 + wid;
    const int q  = NTILES / NW;
    const int rr = NTILES % NW;
    int t0, cnt;
    if (gw < rr) { cnt = q + 1; t0 = gw * cnt; }
    else         { cnt = q;     t0 = rr * (q + 1) + (gw - rr) * q; }
    if (cnt <= 0) return;
    const int tlast = t0 + cnt - 1;

    // ---- prologue: idx for t0 and t0+1, data for t0 ----
    int row0 = (t0 << 4) + col;
    int e0 = (int)((unsigned)row0 / 3u);
    int d0 = row0 - e0 * 3;
    int sA = __builtin_nontemporal_load(src_idx + e0);
    int tA = __builtin_nontemporal_load(dst_idx + e0);

    int tn1 = t0 + 1 <= tlast ? t0 + 1 : tlast;
    int row1 = (tn1 << 4) + col;
    int e1 = (int)((unsigned)row1 / 3u);
    int sB = __builtin_nontemporal_load(src_idx + e1);
    int tB = __builtin_nontemporal_load(dst_idx + e1);

    G4 gcur;
    {
        const float* wp = W + (size_t)e0 * 32 + kk;
        gcur.w0 = __builtin_nontemporal_load((const f32x4*)wp);
        gcur.w1 = __builtin_nontemporal_load((const f32x4*)(wp + 4));
        gcur.xs = *(const short8v*)(xb + ((size_t)sA * 3 + d0) * 32 + kk);
        gcur.xt = *(const short8v*)(xb + ((size_t)tA * 3 + d0) * 32 + kk);
    }

    for (int j = 0; j < cnt; ++j) {
        const int tc = t0 + j;

        // ---- issue next tile's data loads (uses idx prefetched 2 iters ago) ----
        int tn = tc + 1 <= tlast ? tc + 1 : tlast;
        int rown = (tn << 4) + col;
        int en = (int)((unsigned)rown / 3u);
        int dn = rown - en * 3;
        G4 gnxt;
        {
            const float* wp = W + (size_t)en * 32 + kk;
            gnxt.w0 = __builtin_nontemporal_load((const f32x4*)wp);
            gnxt.w1 = __builtin_nontemporal_load((const f32x4*)(wp + 4));
            gnxt.xs = *(const short8v*)(xb + ((size_t)sB * 3 + dn) * 32 + kk);
            gnxt.xt = *(const short8v*)(xb + ((size_t)tB * 3 + dn) * 32 + kk);
        }

        // ---- issue idx loads 2 tiles ahead ----
        int t2 = tc + 2 <= tlast ? tc + 2 : tlast;
        int row2 = (t2 << 4) + col;
        int e2 = (int)((unsigned)row2 / 3u);
        int sC = __builtin_nontemporal_load(src_idx + e2);
        int tC = __builtin_nontemporal_load(dst_idx + e2);

        // ---- compute current tile from gcur ----
        float xsf[8], xtf[8];
        #pragma unroll
        for (int i = 0; i < 8; ++i) {
            xsf[i] = __builtin_bit_cast(float, ((unsigned)(unsigned short)gcur.xs[i]) << 16);
            xtf[i] = __builtin_bit_cast(float, ((unsigned)(unsigned short)gcur.xt[i]) << 16);
        }
        union { short8v v; __hip_bfloat162 h[4]; } ua, ub;
        ua.h[0] = __float22bfloat162_rn(make_float2(gcur.w0.x * xsf[0], gcur.w0.y * xsf[1]));
        ua.h[1] = __float22bfloat162_rn(make_float2(gcur.w0.z * xsf[2], gcur.w0.w * xsf[3]));
        ua.h[2] = __float22bfloat162_rn(make_float2(gcur.w1.x * xsf[4], gcur.w1.y * xsf[5]));
        ua.h[3] = __float22bfloat162_rn(make_float2(gcur.w1.z * xsf[6], gcur.w1.w * xsf[7]));
        ub.h[0] = __float22bfloat162_rn(make_float2(gcur.w0.x * xtf[0], gcur.w0.y * xtf[1]));
        ub.h[1] = __float22bfloat162_rn(make_float2(gcur.w0.z * xtf[2], gcur.w0.w * xtf[3]));
        ub.h[2] = __float22bfloat162_rn(make_float2(gcur.w1.x * xtf[4], gcur.w1.y * xtf[5]));
        ub.h[3] = __float22bfloat162_rn(make_float2(gcur.w1.z * xtf[6], gcur.w1.w * xtf[7]));

        f32x4 acc0 = {0.f, 0.f, 0.f, 0.f};
        f32x4 acc1 = {0.f, 0.f, 0.f, 0.f};
        acc0 = __builtin_amdgcn_mfma_f32_16x16x32_bf16(ua.v, B00, acc0, 0, 0, 0);
        acc0 = __builtin_amdgcn_mfma_f32_16x16x32_bf16(ub.v, B10, acc0, 0, 0, 0);
        acc1 = __builtin_amdgcn_mfma_f32_16x16x32_bf16(ua.v, B01, acc1, 0, 0, 0);
        acc1 = __builtin_amdgcn_mfma_f32_16x16x32_bf16(ub.v, B11, acc1, 0, 0, 0);

        // D: col = lane&15, row = tc*16 + kg*4 + i  — nontemporal stores
        float* op = out + (size_t)((tc << 4) + (kg << 2)) * 32 + col;
        #pragma unroll
        for (int i = 0; i < 4; ++i) {
            __builtin_nontemporal_store(acc0[i], op + (size_t)i * 32);
            __builtin_nontemporal_store(acc1[i], op + (size_t)i * 32 + 16);
        }

        // rotate pipeline registers
        gcur = gnxt;
        sB = sC; tB = tC;
    }
}

extern "C" void kernel_launch(void* const* d_in, const int* in_sizes, int n_in,
                              void* d_out, int out_size, void* d_ws, size_t ws_size,
                              hipStream_t stream) {
    const float* xn  = (const float*)d_in[0];
    const int*   xs  = (const int*)  d_in[1];
    const int*   xd  = (const int*)  d_in[2];
    const float* W   = (const float*)d_in[3];
    const float* M1  = (const float*)d_in[4];
    const float* M2  = (const float*)d_in[5];
    float* out = (float*)d_out;

    unsigned short* mc = (unsigned short*)d_ws;                 // 64*32*2 = 4 KB
    unsigned short* xb = (unsigned short*)((char*)d_ws + 4096); // 9.6 MB bf16 xn

    hipLaunchKernelGGL(build_mc, dim3(8), dim3(256), 0, stream, M1, M2, mc);
    hipLaunchKernelGGL(convert_xn, dim3(1024), dim3(256), 0, stream, xn, xb);
    hipLaunchKernelGGL(n2e_main, dim3(2048), dim3(256), 0, stream,
                       xb, xs, xd, W, mc, out);
}